// Round 14
// baseline (102.396 us; speedup 1.0000x reference)
//
#include <hip/hip_runtime.h>

#define N_USER   300000
#define M_ITEM   700000
#define N_NODES  (N_USER + M_ITEM)
#define DIM      64
#define N_EDGES  1200000
#define BATCH    4096

// ---------------------------------------------------------------------------
// Threefry2x32-20, JAX partitionable path (bit-exact, verified round 2).
// ---------------------------------------------------------------------------
__device__ __forceinline__ unsigned rotl32(unsigned x, int r) {
    return (x << r) | (x >> (32 - r));
}

__device__ __forceinline__ float edge_veff(int e, float val) {
    unsigned ks[3] = {0u, 42u, 0u ^ 42u ^ 0x1BD11BDAu};
    unsigned x0 = ks[0];
    unsigned x1 = (unsigned)e + ks[1];
    const int rotA[4] = {13, 15, 26, 6};
    const int rotB[4] = {17, 29, 16, 24};
#pragma unroll
    for (int g = 0; g < 5; ++g) {
#pragma unroll
        for (int j = 0; j < 4; ++j) {
            int r = (g & 1) ? rotB[j] : rotA[j];
            x0 += x1;
            x1 = rotl32(x1, r);
            x1 ^= x0;
        }
        x0 += ks[(g + 1) % 3];
        x1 += ks[(g + 2) % 3] + (unsigned)(g + 1);
    }
    unsigned bits = x0 ^ x1;
    float u = __uint_as_float((bits >> 9) | 0x3F800000u) - 1.0f;
    return (u >= 0.1f) ? val * (1.0f / 0.9f) : 0.0f;
}

// ---------------------------------------------------------------------------
// P0: head[n] = -1 (grid-stride int4).
// ---------------------------------------------------------------------------
__global__ void fill_kernel(int4* __restrict__ head4) {
    const int TOT4 = N_NODES / 4;  // 250,000
    int tid = blockIdx.x * blockDim.x + threadIdx.x;
    int stride = gridDim.x * blockDim.x;
    int4 m1 = make_int4(-1, -1, -1, -1);
    for (int i = tid; i < TOT4; i += stride) head4[i] = m1;
}

// ---------------------------------------------------------------------------
// P1: push kept edges into per-dst linked lists, AoS node = {nxt, src, val}.
// 4 edges per thread, vectorized int4/float4 loads (N_EDGES % 4 == 0).
// node[e] is only read after the kernel boundary -> exch-then-store is safe.
// ---------------------------------------------------------------------------
__global__ void push_kernel(const int4* __restrict__ esrc4,
                            const int4* __restrict__ edst4,
                            const float4* __restrict__ evals4,
                            int* __restrict__ head,
                            int4* __restrict__ node) {
    int q = blockIdx.x * blockDim.x + threadIdx.x;   // quad index
    if (q >= N_EDGES / 4) return;
    int4 dst = edst4[q];
    int4 src = esrc4[q];
    float4 ev = evals4[q];
    int e0 = q * 4;

    float v0 = edge_veff(e0 + 0, ev.x);
    float v1 = edge_veff(e0 + 1, ev.y);
    float v2 = edge_veff(e0 + 2, ev.z);
    float v3 = edge_veff(e0 + 3, ev.w);

    if (v0 != 0.0f) {
        int old = atomicExch(&head[dst.x], e0 + 0);
        node[e0 + 0] = make_int4(old, src.x, __float_as_int(v0), 0);
    }
    if (v1 != 0.0f) {
        int old = atomicExch(&head[dst.y], e0 + 1);
        node[e0 + 1] = make_int4(old, src.y, __float_as_int(v1), 0);
    }
    if (v2 != 0.0f) {
        int old = atomicExch(&head[dst.z], e0 + 2);
        node[e0 + 2] = make_int4(old, src.z, __float_as_int(v2), 0);
    }
    if (v3 != 0.0f) {
        int old = atomicExch(&head[dst.w], e0 + 3);
        node[e0 + 3] = make_int4(old, src.w, __float_as_int(v3), 0);
    }
}

// ---------------------------------------------------------------------------
// P2: one wave per root (user/item separate), one int4 load per list hop.
// Partials exchanged via LDS inside the 4-wave block.
// ---------------------------------------------------------------------------
__device__ __forceinline__ float emb0(const float* __restrict__ ue,
                                      const float* __restrict__ ie, int s, int d) {
    return (s < N_USER) ? ue[(size_t)s * DIM + d] : ie[(size_t)(s - N_USER) * DIM + d];
}

__device__ __forceinline__ void pull3(int n, int d,
                                      const float* __restrict__ ue,
                                      const float* __restrict__ ie,
                                      const int* __restrict__ head,
                                      const int4* __restrict__ node,
                                      float& u1, float& u2, float& u3) {
    u1 = 0.f; u2 = 0.f; u3 = 0.f;
    for (int e1 = head[n]; e1 != -1; ) {
        int4 n1 = node[e1];
        e1 = n1.x;
        int s1 = n1.y;
        float v1 = __int_as_float(n1.z);
        u1 += v1 * emb0(ue, ie, s1, d);
        float a1 = 0.f, a2 = 0.f;
        for (int e2 = head[s1]; e2 != -1; ) {
            int4 n2 = node[e2];
            e2 = n2.x;
            int s2 = n2.y;
            float v2 = __int_as_float(n2.z);
            a1 += v2 * emb0(ue, ie, s2, d);
            float b1 = 0.f;
            for (int e3 = head[s2]; e3 != -1; ) {
                int4 n3 = node[e3];
                e3 = n3.x;
                b1 += __int_as_float(n3.z) * emb0(ue, ie, n3.y, d);
            }
            a2 += v2 * b1;
        }
        u2 += v1 * a1;
        u3 += v1 * a2;
    }
}

__global__ void out_kernel(const float* __restrict__ user_emb,
                           const float* __restrict__ item_emb,
                           const int* __restrict__ users,
                           const int* __restrict__ items,
                           const int* __restrict__ head,
                           const int4* __restrict__ node,
                           float* __restrict__ ratings,
                           float* __restrict__ inter,
                           float* __restrict__ inter_layers) {
    __shared__ float sh[4][4][DIM];  // [wave][layer][dim]
    int w = threadIdx.x >> 6;        // wave in block: 0..3
    int d = threadIdx.x & 63;
    int b = blockIdx.x * 2 + (w >> 1);
    bool is_item = (w & 1);

    int root = is_item ? (N_USER + items[b]) : users[b];
    float x0 = emb0(user_emb, item_emb, root, d);
    float x1, x2, x3;
    pull3(root, d, user_emb, item_emb, head, node, x1, x2, x3);

    sh[w][0][d] = x0;
    sh[w][1][d] = x1;
    sh[w][2][d] = x2;
    sh[w][3][d] = x3;
    __syncthreads();

    if (!is_item) {
        float i0 = sh[w + 1][0][d];
        float i1 = sh[w + 1][1][d];
        float i2 = sh[w + 1][2][d];
        float i3 = sh[w + 1][3][d];

        size_t base = (size_t)b * 4 * DIM + d;
        inter_layers[base + 0 * DIM] = x0 * i0;
        inter_layers[base + 1 * DIM] = x1 * i1;
        inter_layers[base + 2 * DIM] = x2 * i2;
        inter_layers[base + 3 * DIM] = x3 * i3;

        float lu = (x0 + x1 + x2 + x3) * 0.25f;
        float li = (i0 + i1 + i2 + i3) * 0.25f;
        float p = lu * li;
        inter[(size_t)b * DIM + d] = p;
        float s = p;
#pragma unroll
        for (int off = 32; off > 0; off >>= 1) s += __shfl_down(s, off, 64);
        if (d == 0) ratings[b] = 1.0f / (1.0f + expf(-s));
    }
}

// ---------------------------------------------------------------------------
extern "C" void kernel_launch(void* const* d_in, const int* in_sizes, int n_in,
                              void* d_out, int out_size, void* d_ws, size_t ws_size,
                              hipStream_t stream) {
    const float* user_emb  = (const float*)d_in[0];
    const float* item_emb  = (const float*)d_in[1];
    const float* edge_vals = (const float*)d_in[2];
    const int*   edge_src  = (const int*)d_in[3];
    const int*   edge_dst  = (const int*)d_in[4];
    const int*   users     = (const int*)d_in[5];
    const int*   items     = (const int*)d_in[6];

    float* out          = (float*)d_out;
    float* ratings      = out;                       // [BATCH]
    float* inter        = out + BATCH;               // [BATCH, DIM]
    float* inter_layers = out + BATCH + BATCH * DIM; // [BATCH, 4, DIM]

    char* ws = (char*)d_ws;
    size_t off = 0;
    int* head = (int*)(ws + off); off += (size_t)N_NODES * sizeof(int);
    int4* node = (int4*)(ws + off); off += (size_t)N_EDGES * sizeof(int4);

    const dim3 blk(256);

    fill_kernel<<<512, blk, 0, stream>>>((int4*)head);
    push_kernel<<<(N_EDGES / 4 + 255) / 256, blk, 0, stream>>>(
        (const int4*)edge_src, (const int4*)edge_dst, (const float4*)edge_vals,
        head, (int4*)node);
    out_kernel<<<BATCH / 2, blk, 0, stream>>>(
        user_emb, item_emb, users, items, head, node,
        ratings, inter, inter_layers);
}

// Round 15
// 79.977 us; speedup vs baseline: 1.2803x; 1.2803x over previous
//
#include <hip/hip_runtime.h>

#define N_USER   300000
#define M_ITEM   700000
#define N_NODES  (N_USER + M_ITEM)
#define DIM      64
#define N_EDGES  1200000
#define BATCH    4096

// ---------------------------------------------------------------------------
// Threefry2x32-20, JAX partitionable path (bit-exact, verified round 2).
// ---------------------------------------------------------------------------
__device__ __forceinline__ unsigned rotl32(unsigned x, int r) {
    return (x << r) | (x >> (32 - r));
}

__device__ __forceinline__ float edge_veff(int e, float val) {
    unsigned ks[3] = {0u, 42u, 0u ^ 42u ^ 0x1BD11BDAu};
    unsigned x0 = ks[0];
    unsigned x1 = (unsigned)e + ks[1];
    const int rotA[4] = {13, 15, 26, 6};
    const int rotB[4] = {17, 29, 16, 24};
#pragma unroll
    for (int g = 0; g < 5; ++g) {
#pragma unroll
        for (int j = 0; j < 4; ++j) {
            int r = (g & 1) ? rotB[j] : rotA[j];
            x0 += x1;
            x1 = rotl32(x1, r);
            x1 ^= x0;
        }
        x0 += ks[(g + 1) % 3];
        x1 += ks[(g + 2) % 3] + (unsigned)(g + 1);
    }
    unsigned bits = x0 ^ x1;
    float u = __uint_as_float((bits >> 9) | 0x3F800000u) - 1.0f;
    return (u >= 0.1f) ? val * (1.0f / 0.9f) : 0.0f;
}

// ---------------------------------------------------------------------------
// P0: head[n] = -1 (grid-stride int4).
// ---------------------------------------------------------------------------
__global__ void fill_kernel(int4* __restrict__ head4) {
    const int TOT4 = N_NODES / 4;  // 250,000
    int tid = blockIdx.x * blockDim.x + threadIdx.x;
    int stride = gridDim.x * blockDim.x;
    int4 m1 = make_int4(-1, -1, -1, -1);
    for (int i = tid; i < TOT4; i += stride) head4[i] = m1;
}

// ---------------------------------------------------------------------------
// P1: push kept edges into per-dst linked lists, AoS node = {nxt, src, val}.
// ONE edge per thread: push is atomic-LATENCY-bound (r14 ablation: 4
// edges/thread serialized the exch round-trips and cost +22us) — max thread
// count = max latency hiding. node[e] stores are coalesced (e = tid) and
// only read after the kernel boundary, so exch-then-store is race-free.
// ---------------------------------------------------------------------------
__global__ void push_kernel(const int* __restrict__ esrc,
                            const int* __restrict__ edst,
                            const float* __restrict__ evals,
                            int* __restrict__ head,
                            int4* __restrict__ node) {
    int e = blockIdx.x * blockDim.x + threadIdx.x;
    if (e >= N_EDGES) return;
    float v = edge_veff(e, evals[e]);
    if (v == 0.0f) return;
    int old = atomicExch(&head[edst[e]], e);
    node[e] = make_int4(old, esrc[e], __float_as_int(v), 0);
}

// ---------------------------------------------------------------------------
// P2: one wave per root (user/item separate -> 2x chase parallelism), one
// int4 load per list hop. Partials exchanged via LDS in the 4-wave block.
// ---------------------------------------------------------------------------
__device__ __forceinline__ float emb0(const float* __restrict__ ue,
                                      const float* __restrict__ ie, int s, int d) {
    return (s < N_USER) ? ue[(size_t)s * DIM + d] : ie[(size_t)(s - N_USER) * DIM + d];
}

__device__ __forceinline__ void pull3(int n, int d,
                                      const float* __restrict__ ue,
                                      const float* __restrict__ ie,
                                      const int* __restrict__ head,
                                      const int4* __restrict__ node,
                                      float& u1, float& u2, float& u3) {
    u1 = 0.f; u2 = 0.f; u3 = 0.f;
    for (int e1 = head[n]; e1 != -1; ) {
        int4 n1 = node[e1];
        e1 = n1.x;
        int s1 = n1.y;
        float v1 = __int_as_float(n1.z);
        u1 += v1 * emb0(ue, ie, s1, d);
        float a1 = 0.f, a2 = 0.f;
        for (int e2 = head[s1]; e2 != -1; ) {
            int4 n2 = node[e2];
            e2 = n2.x;
            int s2 = n2.y;
            float v2 = __int_as_float(n2.z);
            a1 += v2 * emb0(ue, ie, s2, d);
            float b1 = 0.f;
            for (int e3 = head[s2]; e3 != -1; ) {
                int4 n3 = node[e3];
                e3 = n3.x;
                b1 += __int_as_float(n3.z) * emb0(ue, ie, n3.y, d);
            }
            a2 += v2 * b1;
        }
        u2 += v1 * a1;
        u3 += v1 * a2;
    }
}

__global__ void out_kernel(const float* __restrict__ user_emb,
                           const float* __restrict__ item_emb,
                           const int* __restrict__ users,
                           const int* __restrict__ items,
                           const int* __restrict__ head,
                           const int4* __restrict__ node,
                           float* __restrict__ ratings,
                           float* __restrict__ inter,
                           float* __restrict__ inter_layers) {
    __shared__ float sh[4][4][DIM];  // [wave][layer][dim]
    int w = threadIdx.x >> 6;        // wave in block: 0..3
    int d = threadIdx.x & 63;
    int b = blockIdx.x * 2 + (w >> 1);
    bool is_item = (w & 1);

    int root = is_item ? (N_USER + items[b]) : users[b];
    float x0 = emb0(user_emb, item_emb, root, d);
    float x1, x2, x3;
    pull3(root, d, user_emb, item_emb, head, node, x1, x2, x3);

    sh[w][0][d] = x0;
    sh[w][1][d] = x1;
    sh[w][2][d] = x2;
    sh[w][3][d] = x3;
    __syncthreads();

    if (!is_item) {
        float i0 = sh[w + 1][0][d];
        float i1 = sh[w + 1][1][d];
        float i2 = sh[w + 1][2][d];
        float i3 = sh[w + 1][3][d];

        size_t base = (size_t)b * 4 * DIM + d;
        inter_layers[base + 0 * DIM] = x0 * i0;
        inter_layers[base + 1 * DIM] = x1 * i1;
        inter_layers[base + 2 * DIM] = x2 * i2;
        inter_layers[base + 3 * DIM] = x3 * i3;

        float lu = (x0 + x1 + x2 + x3) * 0.25f;
        float li = (i0 + i1 + i2 + i3) * 0.25f;
        float p = lu * li;
        inter[(size_t)b * DIM + d] = p;
        float s = p;
#pragma unroll
        for (int off = 32; off > 0; off >>= 1) s += __shfl_down(s, off, 64);
        if (d == 0) ratings[b] = 1.0f / (1.0f + expf(-s));
    }
}

// ---------------------------------------------------------------------------
extern "C" void kernel_launch(void* const* d_in, const int* in_sizes, int n_in,
                              void* d_out, int out_size, void* d_ws, size_t ws_size,
                              hipStream_t stream) {
    const float* user_emb  = (const float*)d_in[0];
    const float* item_emb  = (const float*)d_in[1];
    const float* edge_vals = (const float*)d_in[2];
    const int*   edge_src  = (const int*)d_in[3];
    const int*   edge_dst  = (const int*)d_in[4];
    const int*   users     = (const int*)d_in[5];
    const int*   items     = (const int*)d_in[6];

    float* out          = (float*)d_out;
    float* ratings      = out;                       // [BATCH]
    float* inter        = out + BATCH;               // [BATCH, DIM]
    float* inter_layers = out + BATCH + BATCH * DIM; // [BATCH, 4, DIM]

    char* ws = (char*)d_ws;
    size_t off = 0;
    int* head = (int*)(ws + off); off += (size_t)N_NODES * sizeof(int);
    int4* node = (int4*)(ws + off); off += (size_t)N_EDGES * sizeof(int4);

    const dim3 blk(256);

    fill_kernel<<<512, blk, 0, stream>>>((int4*)head);
    push_kernel<<<(N_EDGES + 255) / 256, blk, 0, stream>>>(
        edge_src, edge_dst, edge_vals, head, (int4*)node);
    out_kernel<<<BATCH / 2, blk, 0, stream>>>(
        user_emb, item_emb, users, items, head, node,
        ratings, inter, inter_layers);
}